// Round 5
// baseline (301.786 us; speedup 1.0000x reference)
//
#include <hip/hip_runtime.h>
#include <math.h>

typedef __attribute__((ext_vector_type(8))) short bf16x8;
typedef __attribute__((ext_vector_type(4))) float f32x4;
typedef __attribute__((ext_vector_type(16))) float f32x16;

#define HID 2048
#define SEQ 2048
#define NH  16
#define DH  128
#define QK_SCALE 0.02209708691207961f  // 1/sqrt(2048)

__device__ __forceinline__ ushort f2bf(float f) {
  union { float f; unsigned u; } v; v.f = f;
  unsigned r = v.u + 0x7fffu + ((v.u >> 16) & 1u);
  return (ushort)(r >> 16);
}

// async global->LDS, 16B per lane. lds ptr must be wave-uniform; HW adds lane*16.
__device__ __forceinline__ void gload16(const ushort* g, ushort* l) {
  __builtin_amdgcn_global_load_lds((const __attribute__((address_space(1))) void*)g,
                                   (__attribute__((address_space(3))) void*)l,
                                   16, 0, 0);
}

#define VMCNT(n) asm volatile("s_waitcnt vmcnt(" #n ")" ::: "memory")
#define BAR()    __builtin_amdgcn_s_barrier()

// ---------- fused transpose fp32 [2048][2048] -> bf16 [2048][2048] (Wt[n][k] = W[k][n]) ----------
__global__ __launch_bounds__(256) void k_transpose4(const float* __restrict__ W0,
                                                    const float* __restrict__ W1,
                                                    const float* __restrict__ W2,
                                                    const float* __restrict__ W3,
                                                    ushort* __restrict__ T0,
                                                    ushort* __restrict__ T3) {
  __shared__ float t[32][33];
  int z = blockIdx.z;
  const float* W = (z == 0) ? W0 : (z == 1) ? W1 : (z == 2) ? W2 : W3;
  ushort* Wt = (z == 3) ? T3 : (T0 + (size_t)z * 2048 * 2048);
  int n0 = blockIdx.x * 32, k0 = blockIdx.y * 32;
  int tx = threadIdx.x, ty = threadIdx.y;
  for (int i = ty; i < 32; i += 8)
    t[i][tx] = W[(size_t)(k0 + i) * HID + n0 + tx];
  __syncthreads();
  for (int i = ty; i < 32; i += 8)
    Wt[(size_t)(n0 + i) * HID + k0 + tx] = f2bf(t[tx][i]);
}

// ---------- RMSNorm: x fp32 [4096][2048] -> xn bf16 ----------
__global__ __launch_bounds__(256) void k_rmsnorm(const float* __restrict__ x,
                                                 const float* __restrict__ w,
                                                 ushort* __restrict__ xn) {
  int row = blockIdx.x;
  const float* xr = x + (size_t)row * HID;
  int base = threadIdx.x * 8;
  float4 a = *(const float4*)(xr + base);
  float4 c = *(const float4*)(xr + base + 4);
  float ss = a.x*a.x + a.y*a.y + a.z*a.z + a.w*a.w
           + c.x*c.x + c.y*c.y + c.z*c.z + c.w*c.w;
  #pragma unroll
  for (int off = 32; off > 0; off >>= 1) ss += __shfl_xor(ss, off);
  __shared__ float red[4];
  if ((threadIdx.x & 63) == 0) red[threadIdx.x >> 6] = ss;
  __syncthreads();
  float tot = red[0] + red[1] + red[2] + red[3];
  float sc = rsqrtf(tot * (1.0f / HID) + 1e-5f);
  float4 wa = *(const float4*)(w + base);
  float4 wc = *(const float4*)(w + base + 4);
  ushort h[8];
  h[0] = f2bf(a.x * sc * wa.x); h[1] = f2bf(a.y * sc * wa.y);
  h[2] = f2bf(a.z * sc * wa.z); h[3] = f2bf(a.w * sc * wa.w);
  h[4] = f2bf(c.x * sc * wc.x); h[5] = f2bf(c.y * sc * wc.y);
  h[6] = f2bf(c.z * sc * wc.z); h[7] = f2bf(c.w * sc * wc.w);
  int4 pk;
  pk.x = h[0] | ((int)h[1] << 16);
  pk.y = h[2] | ((int)h[3] << 16);
  pk.z = h[4] | ((int)h[5] << 16);
  pk.w = h[6] | ((int)h[7] << 16);
  *(int4*)&xn[(size_t)row * HID + base] = pk;
}

// ---------- GEMM v4: R2's verified 128x128 structure + 2-deep counted-vmcnt dbuf ----------
// C[M][N] = A[M][K](bf16) * Bt[N][K](bf16)^T.  4 waves (2x2), 64x64/wave, BK=64.
// LDS 64KB: sA[2][128][64], sB[2][128][64].  STAGE(t+1) issued BEFORE compute(t);
// vmcnt(8) waits tile t's 8 loads, leaves t+1's in flight under the MFMAs (T4).
// Swizzle (R2-verified, 0 conflicts): stage chunk ck^(r&7) pre-applied on the
// global source; read chunk cp = (kk*4+g)^(lane&7) with row&7 == lane&7.
// MODE 0: qkv (N=6144): col<4096 -> bf16 qk; col>=4096 (V) -> transposed vt store.
// MODE 1: out-proj (N=2048): fp32 + residual.
template <int MODE>
__global__ __launch_bounds__(256) void k_gemm4(const ushort* __restrict__ A,
                                               const ushort* __restrict__ Bt,
                                               ushort* __restrict__ obf,
                                               ushort* __restrict__ vt,
                                               float* __restrict__ ofl,
                                               const float* __restrict__ resid,
                                               int K) {
  __shared__ ushort sA[2][128 * 64];
  __shared__ ushort sB[2][128 * 64];
  const int tid = threadIdx.x;
  const int lane = tid & 63, w = tid >> 6;
  const int wr = w >> 1, wc = w & 1;  // 2x2 waves, 64x64 each
  const int bm = blockIdx.y, bn = blockIdx.x;
  const int g = lane >> 4, l15 = lane & 15;
  f32x4 acc[4][4];
  #pragma unroll
  for (int i = 0; i < 4; ++i)
    #pragma unroll
    for (int j = 0; j < 4; ++j) acc[i][j] = f32x4{0.f, 0.f, 0.f, 0.f};

  auto STAGE = [&](int t, int buf) {
    const int k0 = t * 64;
    #pragma unroll
    for (int c = 0; c < 4; ++c) {
      int id = (w * 4 + c) * 64 + lane;
      int r = id >> 3, ck = id & 7;
      int ke = k0 + ((ck ^ (r & 7)) * 8);
      gload16(&A[(size_t)(bm * 128 + r) * K + ke], &sA[buf][(w * 4 + c) * 512]);
      gload16(&Bt[(size_t)(bn * 128 + r) * K + ke], &sB[buf][(w * 4 + c) * 512]);
    }
  };
  auto COMPUTE = [&](int buf) {
    #pragma unroll
    for (int kk = 0; kk < 2; ++kk) {
      bf16x8 aF[4], bF[4];
      #pragma unroll
      for (int i = 0; i < 4; ++i) {
        int row = wr * 64 + i * 16 + l15;   // row&7 == lane&7
        int cp = (kk * 4 + g) ^ (lane & 7);
        aF[i] = *(const bf16x8*)&sA[buf][row * 64 + cp * 8];
      }
      #pragma unroll
      for (int j = 0; j < 4; ++j) {
        int row = wc * 64 + j * 16 + l15;
        int cp = (kk * 4 + g) ^ (lane & 7);
        bF[j] = *(const bf16x8*)&sB[buf][row * 64 + cp * 8];
      }
      #pragma unroll
      for (int i = 0; i < 4; ++i)
        #pragma unroll
        for (int j = 0; j < 4; ++j)
          acc[i][j] = __builtin_amdgcn_mfma_f32_16x16x32_bf16(aF[i], bF[j], acc[i][j], 0, 0, 0);
    }
  };

  const int nt = K / 64;
  STAGE(0, 0);
  #pragma unroll 1
  for (int t = 0; t < nt - 1; ++t) {
    STAGE(t + 1, (t + 1) & 1);
    VMCNT(8);                 // tile t's 8 loads done; t+1's stay in flight
    BAR();
    COMPUTE(t & 1);
    BAR();                    // seal buf (t&1) reads before it's restaged next iter
  }
  VMCNT(0);
  BAR();
  COMPUTE((nt - 1) & 1);

  // C/D layout: col = lane&15, row = (lane>>4)*4 + r
  int rbase = bm * 128 + wr * 64 + g * 4;
  int cbase = bn * 128 + wc * 64 + l15;
  #pragma unroll
  for (int i = 0; i < 4; ++i) {
    #pragma unroll
    for (int j = 0; j < 4; ++j) {
      int col = cbase + j * 16;
      #pragma unroll
      for (int r = 0; r < 4; ++r) {
        int row = rbase + i * 16 + r;
        float v = acc[i][j][r];
        if (MODE == 0) {
          ushort hv = f2bf(v);
          if (col < 4096) {
            obf[(size_t)row * 4096 + col] = hv;
          } else {
            int nv = col - 4096;
            int h = nv >> 7, d = nv & 127;
            int b = row >> 11, s = row & 2047;
            vt[(size_t)((b * NH + h) * DH + d) * SEQ + s] = hv;
          }
        } else {
          ofl[(size_t)row * HID + col] = v + resid[(size_t)row * HID + col];
        }
      }
    }
  }
}

// ---------- flash attention v3: R2 structure + 2-deep counted-vmcnt dbuf ----------
// 4 waves x QBLK=32, KVBLK=64, 32x32x16 MFMA, swapped QK^T, in-register softmax,
// defer-max, P via bf16-pack + shfl_xor(32).  sK[2][64][128], sV[2][128][64] (64KB).
__global__ __launch_bounds__(256, 2) void k_attn3(const ushort* __restrict__ qk,
                                                  const ushort* __restrict__ vt,
                                                  ushort* __restrict__ aout) {
  __shared__ ushort sK[2][64 * 128];
  __shared__ ushort sV[2][128 * 64];
  const int tid = threadIdx.x;
  const int lane = tid & 63, w = tid >> 6;
  const int h2 = lane >> 5;          // half of wave
  const int l31 = lane & 31;
  const int bid = blockIdx.x;
  const int t = bid >> 3;
  const int bh = (bid & 7) + 8 * (t >> 4);
  const int qblk = 15 - (t & 15);
  const int b = bh >> 4, hh = bh & 15;
  const int q0w = qblk * 128 + w * 32;   // this wave's 32 q rows

  bf16x8 qf[8];
  {
    const ushort* qbase = qk + (size_t)(b * SEQ + q0w + l31) * 4096 + hh * DH;
    #pragma unroll
    for (int kk = 0; kk < 8; ++kk) qf[kk] = *(const bf16x8*)&qbase[kk * 16 + h2 * 8];
  }

  f32x16 accO[4];
  #pragma unroll
  for (int i = 0; i < 4; ++i)
    #pragma unroll
    for (int r = 0; r < 16; ++r) accO[i][r] = 0.f;
  float m_r = -1e30f, l_r = 0.f;

  auto STAGE = [&](int tt, int buf) {
    const int t0 = tt * 64;
    #pragma unroll
    for (int c = 0; c < 4; ++c) {
      int id = (w * 4 + c) * 64 + lane;
      int kr = id >> 4, ck = id & 15;   // sK: 256B rows, 16 chunks
      gload16(qk + (size_t)(b * SEQ + t0 + kr) * 4096 + 2048 + hh * DH + ((ck ^ (kr & 7)) * 8),
              &sK[buf][(size_t)(w * 4 + c) * 512]);
      int dr = id >> 3, cv = id & 7;    // sV: 128B rows, 8 chunks
      gload16(vt + (size_t)(bh * DH + dr) * SEQ + t0 + ((cv ^ (dr & 7)) * 8),
              &sV[buf][(size_t)(w * 4 + c) * 512]);
    }
  };

  auto COMPUTE = [&](int tt, int buf) {
    const int t0 = tt * 64;
    f32x16 accS[2];
    #pragma unroll
    for (int i = 0; i < 2; ++i)
      #pragma unroll
      for (int r = 0; r < 16; ++r) accS[i][r] = 0.f;
    #pragma unroll
    for (int kt = 0; kt < 2; ++kt) {
      const int row = kt * 32 + l31;
      #pragma unroll
      for (int kk = 0; kk < 8; ++kk) {
        const int cp = (kk * 2 + h2) ^ (lane & 7);
        bf16x8 kf = *(const bf16x8*)&sK[buf][row * 128 + cp * 8];
        accS[kt] = __builtin_amdgcn_mfma_f32_32x32x16_bf16(kf, qf[kk], accS[kt], 0, 0, 0);
      }
    }
    const int qa = q0w + l31;
    float pmax = -INFINITY;
    if (t0 + 63 <= q0w) {
      #pragma unroll
      for (int kt = 0; kt < 2; ++kt)
        #pragma unroll
        for (int r = 0; r < 16; ++r) {
          float s = accS[kt][r] * QK_SCALE;
          accS[kt][r] = s;
          pmax = fmaxf(pmax, s);
        }
    } else {
      #pragma unroll
      for (int kt = 0; kt < 2; ++kt)
        #pragma unroll
        for (int r = 0; r < 16; ++r) {
          int ka = t0 + kt * 32 + (r & 3) + 8 * (r >> 2) + 4 * h2;
          float s = (ka <= qa) ? accS[kt][r] * QK_SCALE : -INFINITY;
          accS[kt][r] = s;
          pmax = fmaxf(pmax, s);
        }
    }
    pmax = fmaxf(pmax, __shfl_xor(pmax, 32));
    if (__any(pmax > m_r + 8.f)) {   // defer-max: fires on first tile only in practice
      float mn = fmaxf(m_r, pmax);
      float al = __expf(m_r - mn);
      m_r = mn;
      l_r *= al;
      #pragma unroll
      for (int r = 0; r < 16; ++r) {
        float ar = __shfl(al, (r & 3) + 8 * (r >> 2) + 4 * h2);
        #pragma unroll
        for (int ds = 0; ds < 4; ++ds) accO[ds][r] *= ar;
      }
    }
    float rs = 0.f;
    #pragma unroll
    for (int kt = 0; kt < 2; ++kt)
      #pragma unroll
      for (int r = 0; r < 16; ++r) {
        float p = __expf(accS[kt][r] - m_r);
        rs += p;
        accS[kt][r] = p;
      }
    rs += __shfl_xor(rs, 32);
    l_r += rs;
    uint W[2][4][2];
    #pragma unroll
    for (int kt = 0; kt < 2; ++kt)
      #pragma unroll
      for (int bq = 0; bq < 4; ++bq)
        #pragma unroll
        for (int w2 = 0; w2 < 2; ++w2) {
          uint u0 = __float_as_uint(accS[kt][bq * 4 + w2 * 2]);
          uint u1 = __float_as_uint(accS[kt][bq * 4 + w2 * 2 + 1]);
          W[kt][bq][w2] = (u0 >> 16) | (u1 & 0xffff0000u);
        }
    #pragma unroll
    for (int kc = 0; kc < 4; ++kc) {
      const int kt = kc >> 1, pq = kc & 1;
      uint X0 = W[kt][2 * pq][0],     X1 = W[kt][2 * pq][1];
      uint Y0 = W[kt][2 * pq + 1][0], Y1 = W[kt][2 * pq + 1][1];
      uint sx0 = (uint)__shfl_xor((int)X0, 32);
      uint sx1 = (uint)__shfl_xor((int)X1, 32);
      uint sy0 = (uint)__shfl_xor((int)Y0, 32);
      uint sy1 = (uint)__shfl_xor((int)Y1, 32);
      union { uint u[4]; bf16x8 v; } pu;
      pu.u[0] = h2 ? sy0 : X0;
      pu.u[1] = h2 ? sy1 : X1;
      pu.u[2] = h2 ? Y0 : sx0;
      pu.u[3] = h2 ? Y1 : sx1;
      #pragma unroll
      for (int ds = 0; ds < 4; ++ds) {
        const int dr = ds * 32 + l31;
        const int cp = (kc * 2 + h2) ^ (lane & 7);
        bf16x8 vf = *(const bf16x8*)&sV[buf][dr * 64 + cp * 8];
        accO[ds] = __builtin_amdgcn_mfma_f32_32x32x16_bf16(pu.v, vf, accO[ds], 0, 0, 0);
      }
    }
  };

  const int ntile = 2 * qblk + 2;
  STAGE(0, 0);
  #pragma unroll 1
  for (int tt = 0; tt < ntile - 1; ++tt) {
    STAGE(tt + 1, (tt + 1) & 1);
    VMCNT(8);                 // tile tt's 8 loads done; tt+1's in flight
    BAR();
    if (tt * 64 <= q0w + 31) COMPUTE(tt, tt & 1);
    BAR();
  }
  VMCNT(0);
  BAR();
  COMPUTE(ntile - 1, (ntile - 1) & 1);   // last tile is always active for all waves

  float linv = 1.f / l_r;
  #pragma unroll
  for (int r = 0; r < 16; ++r) {
    int qrel = (r & 3) + 8 * (r >> 2) + 4 * h2;
    float li = __shfl(linv, qrel);
    #pragma unroll
    for (int ds = 0; ds < 4; ++ds) {
      aout[(size_t)(b * SEQ + q0w + qrel) * HID + hh * DH + ds * 32 + l31] =
          f2bf(accO[ds][r] * li);
    }
  }
}

extern "C" void kernel_launch(void* const* d_in, const int* in_sizes, int n_in,
                              void* d_out, int out_size, void* d_ws, size_t ws_size,
                              hipStream_t stream) {
  const float* x     = (const float*)d_in[0];
  const float* rms_w = (const float*)d_in[1];
  const float* Wq    = (const float*)d_in[2];
  const float* Wk    = (const float*)d_in[3];
  const float* Wv    = (const float*)d_in[4];
  const float* Wo    = (const float*)d_in[5];
  float* out = (float*)d_out;

  char* ws = (char*)d_ws;
  ushort* WqkvT = (ushort*)ws; ws += (size_t)6144 * 2048 * 2;  // [6144][2048]
  ushort* WoT   = (ushort*)ws; ws += (size_t)2048 * 2048 * 2;  // [2048][2048]
  ushort* xn    = (ushort*)ws; ws += (size_t)4096 * 2048 * 2;  // [4096][2048]
  ushort* qkbuf = (ushort*)ws; ws += (size_t)4096 * 4096 * 2;  // [4096][4096]
  ushort* vt    = (ushort*)ws; ws += (size_t)4096 * 2048 * 2;  // [(b,h,d)][2048]
  ushort* aout  = (ushort*)ws; ws += (size_t)4096 * 2048 * 2;  // [4096][2048]

  // fused weight transposes (4 matrices in one launch)
  k_transpose4<<<dim3(64, 64, 4), dim3(32, 8), 0, stream>>>(Wq, Wk, Wv, Wo, WqkvT, WoT);

  k_rmsnorm<<<4096, 256, 0, stream>>>(x, rms_w, xn);

  // QKV: M=4096, N=6144, K=2048 (bn-fast plain grid — measured best L2 behavior)
  k_gemm4<0><<<dim3(48, 32), 256, 0, stream>>>(xn, WqkvT, qkbuf, vt, nullptr, nullptr, 2048);

  // attention: 512 blocks (16 q-blocks x 32 bh)
  k_attn3<<<512, 256, 0, stream>>>(qkbuf, vt, aout);

  // out = attn @ Wo + x : M=4096, N=2048, K=2048
  k_gemm4<1><<<dim3(16, 32), 256, 0, stream>>>(aout, WoT, nullptr, nullptr, out, x, 2048);
}

// Round 6
// 296.864 us; speedup vs baseline: 1.0166x; 1.0166x over previous
//
#include <hip/hip_runtime.h>
#include <math.h>

typedef __attribute__((ext_vector_type(8))) short bf16x8;
typedef __attribute__((ext_vector_type(4))) float f32x4;
typedef __attribute__((ext_vector_type(16))) float f32x16;

#define HID 2048
#define SEQ 2048
#define NH  16
#define DH  128
#define QK_SCALE 0.02209708691207961f  // 1/sqrt(2048)

__device__ __forceinline__ ushort f2bf(float f) {
  union { float f; unsigned u; } v; v.f = f;
  unsigned r = v.u + 0x7fffu + ((v.u >> 16) & 1u);
  return (ushort)(r >> 16);
}

// async global->LDS, 16B per lane. lds ptr must be wave-uniform; HW adds lane*16.
__device__ __forceinline__ void gload16(const ushort* g, ushort* l) {
  __builtin_amdgcn_global_load_lds((const __attribute__((address_space(1))) void*)g,
                                   (__attribute__((address_space(3))) void*)l,
                                   16, 0, 0);
}

#define VMCNT(n) asm volatile("s_waitcnt vmcnt(" #n ")" ::: "memory")
#define BAR()    __builtin_amdgcn_s_barrier()

// ---------- fused transpose fp32 [2048][2048] -> bf16 [2048][2048] (Wt[n][k] = W[k][n]) ----------
__global__ __launch_bounds__(256) void k_transpose4(const float* __restrict__ W0,
                                                    const float* __restrict__ W1,
                                                    const float* __restrict__ W2,
                                                    const float* __restrict__ W3,
                                                    ushort* __restrict__ T0,
                                                    ushort* __restrict__ T3) {
  __shared__ float t[32][33];
  int z = blockIdx.z;
  const float* W = (z == 0) ? W0 : (z == 1) ? W1 : (z == 2) ? W2 : W3;
  ushort* Wt = (z == 3) ? T3 : (T0 + (size_t)z * 2048 * 2048);
  int n0 = blockIdx.x * 32, k0 = blockIdx.y * 32;
  int tx = threadIdx.x, ty = threadIdx.y;
  for (int i = ty; i < 32; i += 8)
    t[i][tx] = W[(size_t)(k0 + i) * HID + n0 + tx];
  __syncthreads();
  for (int i = ty; i < 32; i += 8)
    Wt[(size_t)(n0 + i) * HID + k0 + tx] = f2bf(t[tx][i]);
}

// ---------- RMSNorm: x fp32 [4096][2048] -> xn bf16 ----------
__global__ __launch_bounds__(256) void k_rmsnorm(const float* __restrict__ x,
                                                 const float* __restrict__ w,
                                                 ushort* __restrict__ xn) {
  int row = blockIdx.x;
  const float* xr = x + (size_t)row * HID;
  int base = threadIdx.x * 8;
  float4 a = *(const float4*)(xr + base);
  float4 c = *(const float4*)(xr + base + 4);
  float ss = a.x*a.x + a.y*a.y + a.z*a.z + a.w*a.w
           + c.x*c.x + c.y*c.y + c.z*c.z + c.w*c.w;
  #pragma unroll
  for (int off = 32; off > 0; off >>= 1) ss += __shfl_xor(ss, off);
  __shared__ float red[4];
  if ((threadIdx.x & 63) == 0) red[threadIdx.x >> 6] = ss;
  __syncthreads();
  float tot = red[0] + red[1] + red[2] + red[3];
  float sc = rsqrtf(tot * (1.0f / HID) + 1e-5f);
  float4 wa = *(const float4*)(w + base);
  float4 wc = *(const float4*)(w + base + 4);
  ushort h[8];
  h[0] = f2bf(a.x * sc * wa.x); h[1] = f2bf(a.y * sc * wa.y);
  h[2] = f2bf(a.z * sc * wa.z); h[3] = f2bf(a.w * sc * wa.w);
  h[4] = f2bf(c.x * sc * wc.x); h[5] = f2bf(c.y * sc * wc.y);
  h[6] = f2bf(c.z * sc * wc.z); h[7] = f2bf(c.w * sc * wc.w);
  int4 pk;
  pk.x = h[0] | ((int)h[1] << 16);
  pk.y = h[2] | ((int)h[3] << 16);
  pk.z = h[4] | ((int)h[5] << 16);
  pk.w = h[6] | ((int)h[7] << 16);
  *(int4*)&xn[(size_t)row * HID + base] = pk;
}

// ---------- GEMM v5: ring-4 counted-vmcnt pipeline (R3 structure) + plain grid ----------
// C[M][N] = A[M][K](bf16) * Bt[N][K](bf16)^T.  BM=256, BN=128, 8 waves (4Mx2N,
// per-wave 64x64, acc[4][4]).  LDS = 4 chunks x (A 256x32 + B 128x32) = 96KB.
// Slice s (k=32) computed from chunk s&3 while s+1,s+2 in flight and s+3 issues:
// entry wait vmcnt(6) (= 3 loads/slice x 2 slices), never 0 in main loop (T4).
// Swizzle (R3-verified, 0 conflicts): 16B chunk cp = ck ^ ((row>>1)&3).
// Grid: plain bn-fast / bm-slow (R2-measured FETCH 94MB; XCD-grouped variant
// measured 217MB HBM -> removed).
// MODE 0: qkv (N=6144): col<4096 -> bf16 qk; col>=4096 (V) -> transposed vt store.
// MODE 1: out-proj (N=2048): fp32 + residual.
template <int MODE>
__global__ __launch_bounds__(512, 2) void k_gemm5(const ushort* __restrict__ A,
                                                  const ushort* __restrict__ Bt,
                                                  ushort* __restrict__ obf,
                                                  ushort* __restrict__ vt,
                                                  float* __restrict__ ofl,
                                                  const float* __restrict__ resid) {
  constexpr int K = 2048, NS = 64;                  // 64 k32-slices
  __shared__ ushort lds[4][12288];                  // chunk: A[256][32] + B[128][32]
  const int tid = threadIdx.x;
  const int lane = tid & 63, w = tid >> 6;
  const int wm = w >> 1, wn = w & 1;
  const int g = lane >> 4, l15 = lane & 15;
  const int bm = blockIdx.y, bn = blockIdx.x;

  f32x4 acc[4][4];
  #pragma unroll
  for (int i = 0; i < 4; ++i)
    #pragma unroll
    for (int j = 0; j < 4; ++j) acc[i][j] = f32x4{0.f, 0.f, 0.f, 0.f};

  auto STAGE = [&](int s) {
    const int ch = s & 3, k0 = s * 32;
    #pragma unroll
    for (int c = 0; c < 2; ++c) {                   // A: 2 x 8KB
      int idx = c * 512 + tid;
      int r = idx >> 2, cp = idx & 3;
      int ck = cp ^ ((r >> 1) & 3);
      gload16(&A[(size_t)(bm * 256 + r) * K + k0 + ck * 8],
              &lds[ch][(c * 8 + w) * 512]);
    }
    {                                                // B: 1 x 8KB
      int r = tid >> 2, cp = tid & 3;
      int ck = cp ^ ((r >> 1) & 3);
      gload16(&Bt[(size_t)(bn * 128 + r) * K + k0 + ck * 8],
              &lds[ch][8192 + w * 512]);
    }
  };

  auto COMPUTE = [&](int s) {
    const ushort* La = lds[s & 3];
    const ushort* Lb = La + 8192;
    bf16x8 aF[4], bF[4];
    #pragma unroll
    for (int i = 0; i < 4; ++i) {
      int row = wm * 64 + i * 16 + l15;
      int cp = g ^ ((row >> 1) & 3);
      aF[i] = *(const bf16x8*)&La[row * 32 + cp * 8];
    }
    #pragma unroll
    for (int j = 0; j < 4; ++j) {
      int row = wn * 64 + j * 16 + l15;
      int cp = g ^ ((row >> 1) & 3);
      bF[j] = *(const bf16x8*)&Lb[row * 32 + cp * 8];
    }
    __builtin_amdgcn_s_setprio(1);
    #pragma unroll
    for (int i = 0; i < 4; ++i)
      #pragma unroll
      for (int j = 0; j < 4; ++j)
        acc[i][j] = __builtin_amdgcn_mfma_f32_16x16x32_bf16(aF[i], bF[j], acc[i][j], 0, 0, 0);
    __builtin_amdgcn_s_setprio(0);
  };

  STAGE(0); STAGE(1); STAGE(2);                     // 9 loads in flight
  #pragma unroll 1
  for (int s = 0; s <= NS - 4; ++s) {
    VMCNT(6);                                       // drain slice s's 3 loads
    BAR();
    __builtin_amdgcn_sched_barrier(0);
    STAGE(s + 3);                                   // into chunk freed by slice s-1
    COMPUTE(s);
  }
  VMCNT(6); BAR(); __builtin_amdgcn_sched_barrier(0);
  COMPUTE(NS - 3);
  VMCNT(3); BAR(); __builtin_amdgcn_sched_barrier(0);
  COMPUTE(NS - 2);
  VMCNT(0); BAR(); __builtin_amdgcn_sched_barrier(0);
  COMPUTE(NS - 1);

  // C/D layout: col = lane&15, row = (lane>>4)*4 + r
  int rbase = bm * 256 + wm * 64 + g * 4;
  int cbase = bn * 128 + wn * 64 + l15;
  #pragma unroll
  for (int i = 0; i < 4; ++i) {
    #pragma unroll
    for (int j = 0; j < 4; ++j) {
      int col = cbase + j * 16;
      #pragma unroll
      for (int r = 0; r < 4; ++r) {
        int row = rbase + i * 16 + r;
        float v = acc[i][j][r];
        if (MODE == 0) {
          ushort hv = f2bf(v);
          if (col < 4096) {
            obf[(size_t)row * 4096 + col] = hv;
          } else {
            int nv = col - 4096;
            int h = nv >> 7, d = nv & 127;
            int b = row >> 11, s = row & 2047;
            vt[(size_t)((b * NH + h) * DH + d) * SEQ + s] = hv;
          }
        } else {
          ofl[(size_t)row * HID + col] = v + resid[(size_t)row * HID + col];
        }
      }
    }
  }
}

// ---------- flash attention (R2-verified): 4 waves x QBLK=32, KVBLK=64, 32x32x16 ----------
__global__ __launch_bounds__(256, 2) void k_attn2(const ushort* __restrict__ qk,
                                                  const ushort* __restrict__ vt,
                                                  ushort* __restrict__ aout) {
  __shared__ ushort sK[64 * 128];
  __shared__ ushort sV[128 * 64];
  const int tid = threadIdx.x;
  const int lane = tid & 63, w = tid >> 6;
  const int h2 = lane >> 5;          // half of wave
  const int l31 = lane & 31;
  const int bid = blockIdx.x;
  const int t = bid >> 3;
  const int bh = (bid & 7) + 8 * (t >> 4);
  const int qblk = 15 - (t & 15);
  const int b = bh >> 4, hh = bh & 15;
  const int q0w = qblk * 128 + w * 32;   // this wave's 32 q rows

  bf16x8 qf[8];
  {
    const ushort* qbase = qk + (size_t)(b * SEQ + q0w + l31) * 4096 + hh * DH;
    #pragma unroll
    for (int kk = 0; kk < 8; ++kk) qf[kk] = *(const bf16x8*)&qbase[kk * 16 + h2 * 8];
  }

  f32x16 accO[4];
  #pragma unroll
  for (int i = 0; i < 4; ++i)
    #pragma unroll
    for (int r = 0; r < 16; ++r) accO[i][r] = 0.f;
  float m_r = -1e30f, l_r = 0.f;

  const int ntile = 2 * qblk + 2;
  for (int tt = 0; tt < ntile; ++tt) {
    const int t0 = tt * 64;
    #pragma unroll
    for (int c = 0; c < 4; ++c) {
      int id = (w * 4 + c) * 64 + lane;
      int kr = id >> 4, ck = id & 15;   // sK: 256B rows, 16 chunks
      gload16(qk + (size_t)(b * SEQ + t0 + kr) * 4096 + 2048 + hh * DH + ((ck ^ (kr & 7)) * 8),
              ((ushort*)sK) + (size_t)(w * 4 + c) * 512);
      int dr = id >> 3, cv = id & 7;    // sV: 128B rows, 8 chunks
      gload16(vt + (size_t)(bh * DH + dr) * SEQ + t0 + ((cv ^ (dr & 7)) * 8),
              ((ushort*)sV) + (size_t)(w * 4 + c) * 512);
    }
    __syncthreads();

    if (t0 <= q0w + 31) {
      f32x16 accS[2];
      #pragma unroll
      for (int i = 0; i < 2; ++i)
        #pragma unroll
        for (int r = 0; r < 16; ++r) accS[i][r] = 0.f;
      #pragma unroll
      for (int kt = 0; kt < 2; ++kt) {
        const int row = kt * 32 + l31;
        #pragma unroll
        for (int kk = 0; kk < 8; ++kk) {
          const int cp = (kk * 2 + h2) ^ (lane & 7);
          bf16x8 kf = *(const bf16x8*)&sK[row * 128 + cp * 8];
          accS[kt] = __builtin_amdgcn_mfma_f32_32x32x16_bf16(kf, qf[kk], accS[kt], 0, 0, 0);
        }
      }
      const int qa = q0w + l31;
      float pmax = -INFINITY;
      if (t0 + 63 <= q0w) {
        #pragma unroll
        for (int kt = 0; kt < 2; ++kt)
          #pragma unroll
          for (int r = 0; r < 16; ++r) {
            float s = accS[kt][r] * QK_SCALE;
            accS[kt][r] = s;
            pmax = fmaxf(pmax, s);
          }
      } else {
        #pragma unroll
        for (int kt = 0; kt < 2; ++kt)
          #pragma unroll
          for (int r = 0; r < 16; ++r) {
            int ka = t0 + kt * 32 + (r & 3) + 8 * (r >> 2) + 4 * h2;
            float s = (ka <= qa) ? accS[kt][r] * QK_SCALE : -INFINITY;
            accS[kt][r] = s;
            pmax = fmaxf(pmax, s);
          }
      }
      pmax = fmaxf(pmax, __shfl_xor(pmax, 32));
      if (__any(pmax > m_r + 8.f)) {
        float mn = fmaxf(m_r, pmax);
        float al = __expf(m_r - mn);
        m_r = mn;
        l_r *= al;
        #pragma unroll
        for (int r = 0; r < 16; ++r) {
          float ar = __shfl(al, (r & 3) + 8 * (r >> 2) + 4 * h2);
          #pragma unroll
          for (int ds = 0; ds < 4; ++ds) accO[ds][r] *= ar;
        }
      }
      float rs = 0.f;
      #pragma unroll
      for (int kt = 0; kt < 2; ++kt)
        #pragma unroll
        for (int r = 0; r < 16; ++r) {
          float p = __expf(accS[kt][r] - m_r);
          rs += p;
          accS[kt][r] = p;
        }
      rs += __shfl_xor(rs, 32);
      l_r += rs;
      uint W[2][4][2];
      #pragma unroll
      for (int kt = 0; kt < 2; ++kt)
        #pragma unroll
        for (int bq = 0; bq < 4; ++bq)
          #pragma unroll
          for (int w2 = 0; w2 < 2; ++w2) {
            uint u0 = __float_as_uint(accS[kt][bq * 4 + w2 * 2]);
            uint u1 = __float_as_uint(accS[kt][bq * 4 + w2 * 2 + 1]);
            W[kt][bq][w2] = (u0 >> 16) | (u1 & 0xffff0000u);
          }
      #pragma unroll
      for (int kc = 0; kc < 4; ++kc) {
        const int kt = kc >> 1, pq = kc & 1;
        uint X0 = W[kt][2 * pq][0],     X1 = W[kt][2 * pq][1];
        uint Y0 = W[kt][2 * pq + 1][0], Y1 = W[kt][2 * pq + 1][1];
        uint sx0 = (uint)__shfl_xor((int)X0, 32);
        uint sx1 = (uint)__shfl_xor((int)X1, 32);
        uint sy0 = (uint)__shfl_xor((int)Y0, 32);
        uint sy1 = (uint)__shfl_xor((int)Y1, 32);
        union { uint u[4]; bf16x8 v; } pu;
        pu.u[0] = h2 ? sy0 : X0;
        pu.u[1] = h2 ? sy1 : X1;
        pu.u[2] = h2 ? Y0 : sx0;
        pu.u[3] = h2 ? Y1 : sx1;
        #pragma unroll
        for (int ds = 0; ds < 4; ++ds) {
          const int dr = ds * 32 + l31;
          const int cp = (kc * 2 + h2) ^ (lane & 7);
          bf16x8 vf = *(const bf16x8*)&sV[dr * 64 + cp * 8];
          accO[ds] = __builtin_amdgcn_mfma_f32_32x32x16_bf16(pu.v, vf, accO[ds], 0, 0, 0);
        }
      }
    }
    __syncthreads();
  }

  float linv = 1.f / l_r;
  #pragma unroll
  for (int r = 0; r < 16; ++r) {
    int qrel = (r & 3) + 8 * (r >> 2) + 4 * h2;
    float li = __shfl(linv, qrel);
    #pragma unroll
    for (int ds = 0; ds < 4; ++ds) {
      aout[(size_t)(b * SEQ + q0w + qrel) * HID + hh * DH + ds * 32 + l31] =
          f2bf(accO[ds][r] * li);
    }
  }
}

extern "C" void kernel_launch(void* const* d_in, const int* in_sizes, int n_in,
                              void* d_out, int out_size, void* d_ws, size_t ws_size,
                              hipStream_t stream) {
  const float* x     = (const float*)d_in[0];
  const float* rms_w = (const float*)d_in[1];
  const float* Wq    = (const float*)d_in[2];
  const float* Wk    = (const float*)d_in[3];
  const float* Wv    = (const float*)d_in[4];
  const float* Wo    = (const float*)d_in[5];
  float* out = (float*)d_out;

  char* ws = (char*)d_ws;
  ushort* WqkvT = (ushort*)ws; ws += (size_t)6144 * 2048 * 2;  // [6144][2048]
  ushort* WoT   = (ushort*)ws; ws += (size_t)2048 * 2048 * 2;  // [2048][2048]
  ushort* xn    = (ushort*)ws; ws += (size_t)4096 * 2048 * 2;  // [4096][2048]
  ushort* qkbuf = (ushort*)ws; ws += (size_t)4096 * 4096 * 2;  // [4096][4096]
  ushort* vt    = (ushort*)ws; ws += (size_t)4096 * 2048 * 2;  // [(b,h,d)][2048]
  ushort* aout  = (ushort*)ws; ws += (size_t)4096 * 2048 * 2;  // [4096][2048]

  // fused weight transposes (4 matrices in one launch)
  k_transpose4<<<dim3(64, 64, 4), dim3(32, 8), 0, stream>>>(Wq, Wk, Wv, Wo, WqkvT, WoT);

  k_rmsnorm<<<4096, 256, 0, stream>>>(x, rms_w, xn);

  // QKV: M=4096, N=6144, K=2048.  BM=256 x BN=128 -> grid 48 x 16, bn-fast.
  k_gemm5<0><<<dim3(48, 16), 512, 0, stream>>>(xn, WqkvT, qkbuf, vt, nullptr, nullptr);

  // attention: 512 blocks (16 q-blocks x 32 bh)
  k_attn2<<<512, 256, 0, stream>>>(qkbuf, vt, aout);

  // out = attn @ Wo + x : M=4096, N=2048 -> grid 16 x 16
  k_gemm5<1><<<dim3(16, 16), 512, 0, stream>>>(aout, WoT, nullptr, nullptr, out, x);
}